// Round 1
// baseline (337.608 us; speedup 1.0000x reference)
//
#include <hip/hip_runtime.h>
#include <math.h>

#define Bn 4
#define Ln 1024
#define Sn 1024
#define Hn 8
#define En 64

typedef __attribute__((ext_vector_type(4))) float f32x4;
typedef __attribute__((ext_vector_type(8))) _Float16 h16x8;
typedef __attribute__((ext_vector_type(4))) _Float16 h16x4;

__device__ __forceinline__ float frcp(float x) { return __builtin_amdgcn_rcpf(x); }

__device__ __forceinline__ void gl_lds16(const void* g, void* l) {
    __builtin_amdgcn_global_load_lds(
        (const __attribute__((address_space(1))) unsigned int*)g,
        (__attribute__((address_space(3))) unsigned int*)l, 16, 0, 0);
}

// ---------------------------------------------------------------------------
// prep: split Q,K fp32 -> f16 hi/lo in [bh][row][e] XOR-swizzled rows (16B
// chunk c stored at c^(row&7)); V -> f16 transposed tiles [bh][stile][d][64]
// with the same swizzle. Makes the hot kernel's staging pure global_load_lds.
// ---------------------------------------------------------------------------
__global__ __launch_bounds__(256) void prep(
    const float* __restrict__ Q, const float* __restrict__ K,
    const float* __restrict__ V,
    _Float16* __restrict__ Qh, _Float16* __restrict__ Ql,
    _Float16* __restrict__ Kh, _Float16* __restrict__ Kl,
    _Float16* __restrict__ Vt) {
    __shared__ float vlds[64][69];
    const int st = blockIdx.x;   // s-tile 0..15
    const int bh = blockIdx.y;   // 0..31
    const int b = bh >> 3, h = bh & 7;
    const int tid = threadIdx.x;
    const int s0 = st * 64;

#pragma unroll
    for (int i = 0; i < 4; ++i) {
        int idx = tid + 256 * i;     // 0..1023
        int r = idx >> 4;            // row 0..63
        int c4 = (idx & 15) << 2;    // e 0,4..60
        size_t gin = (((size_t)b * Ln + s0 + r) * Hn + h) * En + c4;
        f32x4 qv = *(const f32x4*)(Q + gin);
        f32x4 kv = *(const f32x4*)(K + gin);
        f32x4 vv = *(const f32x4*)(V + gin);
        vlds[r][c4 + 0] = vv.x; vlds[r][c4 + 1] = vv.y;
        vlds[r][c4 + 2] = vv.z; vlds[r][c4 + 3] = vv.w;
        h16x4 qh4, ql4, kh4, kl4;
#pragma unroll
        for (int j = 0; j < 4; ++j) {
            float x = qv[j];
            _Float16 hx = (_Float16)x;
            qh4[j] = hx; ql4[j] = (_Float16)(x - (float)hx);
            float y = kv[j];
            _Float16 hy = (_Float16)y;
            kh4[j] = hy; kl4[j] = (_Float16)(y - (float)hy);
        }
        size_t ob = ((size_t)bh * 1024 + s0 + r) * 64 + ((((c4 >> 3) ^ (r & 7)) << 3) + (c4 & 7));
        *(h16x4*)(Qh + ob) = qh4; *(h16x4*)(Ql + ob) = ql4;
        *(h16x4*)(Kh + ob) = kh4; *(h16x4*)(Kl + ob) = kl4;
    }
    __syncthreads();
    // transposed V tile: Vt[bh][st][d][s-local], swizzled rows
#pragma unroll
    for (int i = 0; i < 4; ++i) {
        int idx = tid + 256 * i;
        int d = idx >> 4;            // 0..63
        int sg = (idx & 15) << 2;    // 0..60
        h16x4 v4;
#pragma unroll
        for (int j = 0; j < 4; ++j) v4[j] = (_Float16)vlds[sg + j][d];
        size_t ob = (((size_t)bh * 16 + st) * 64 + d) * 64 + ((((sg >> 3) ^ (d & 7)) << 3) + (sg & 7));
        *(h16x4*)(Vt + ob) = v4;
    }
}

// ---------------------------------------------------------------------------
// fused: per (b,h,64-l-tile, s-half) block, 8 chunks of 64 s:
//   global_load_lds staging of pre-split K/Q hi/lo + V^T (swizzled, no VALU)
//   comm = acc1 - acc2 via 6 f16-split MFMA chains (2 accumulators)
//   tanh -> tanh-GELU -> gumbel-sigmoid -> hard mask -> A store + entropy
//   P -> LDS -> PV f16 MFMA; V and entropy finalized with atomics.
// LDS 49 KB, launch_bounds(256,3) -> 3 blocks/CU; grid 1024 blocks.
// ---------------------------------------------------------------------------
__global__ __launch_bounds__(256, 3) void fused_lie(
    const _Float16* __restrict__ Qh, const _Float16* __restrict__ Ql,
    const _Float16* __restrict__ Kh, const _Float16* __restrict__ Kl,
    const _Float16* __restrict__ Vt,
    const float* __restrict__ phi, const float* __restrict__ u,
    const float* __restrict__ hard,
    const float* __restrict__ p_lg, const float* __restrict__ p_lt,
    const float* __restrict__ p_ltc,
    float* __restrict__ Aout, float* __restrict__ Vout,
    float* __restrict__ entOut) {
    __shared__ __align__(16) _Float16 kbh[4096];
    __shared__ __align__(16) _Float16 kbl[4096];
    __shared__ __align__(16) _Float16 qbh[4096];
    __shared__ __align__(16) _Float16 qbl[4096];
    __shared__ __align__(16) _Float16 vbt[4096];
    __shared__ __align__(16) _Float16 plds[4][16 * 72];

    const int bx = blockIdx.x;
    const int lt = bx >> 1, sh = bx & 1;
    const int h = blockIdx.y, b = blockIdx.z;
    const int bh = b * Hn + h;
    const int tid = threadIdx.x;
    const int w = tid >> 6;
    const int lane = tid & 63;
    const int q = lane >> 4;
    const int n = lane & 15;
    const int swz = n & 7;
    const int l0 = lt * 64;

    const float gain = fminf(fmaxf(expf(p_lg[0]), 1e-3f), 1000.0f);
    const float tauc = fminf(fmaxf(expf(p_ltc[0]), 1e-3f), 10.0f);
    const float c2 = 2.0f * gain / tauc;
    const float tau = fminf(fmaxf(expf(p_lt[0]), 0.1f), 5.0f);
    const float itau = 1.0f / tau;

    // A-side fragments (registers): rows l0+w*16+n, k = q*8+j (+32*kh)
    h16x8 QAh[2], QAl[2], KAh[2], KAl[2];
    {
        const size_t ab = ((size_t)bh * 1024 + l0 + w * 16 + n) * 64;
#pragma unroll
        for (int kh = 0; kh < 2; ++kh) {
            size_t off = ab + (((q + kh * 4) ^ swz) << 3);
            QAh[kh] = *(const h16x8*)(Qh + off);
            QAl[kh] = *(const h16x8*)(Ql + off);
            KAh[kh] = *(const h16x8*)(Kh + off);
            KAl[kh] = *(const h16x8*)(Kl + off);
        }
    }

    f32x4 accV[4];
#pragma unroll
    for (int i = 0; i < 4; ++i) accV[i] = (f32x4){0.f, 0.f, 0.f, 0.f};
    float entp[4] = {0.f, 0.f, 0.f, 0.f};

    const int lbase = l0 + w * 16 + q * 4;

    for (int stc = 0; stc < 8; ++stc) {
        const int st = sh * 8 + stc;
        const int s0 = st * 64;
        if (stc) __syncthreads();

        // ---- async staging: 5 tiles x 8KB via global_load_lds dwordx4 ----
        {
            const size_t sb = ((size_t)bh * 1024 + s0) * 64;   // halves
            const size_t vb = (((size_t)bh * 16 + st) * 64) * 64;
#pragma unroll
            for (int i = 0; i < 2; ++i) {
                int hoff = w * 1024 + i * 512 + lane * 8;      // halves
                gl_lds16(Kh + sb + hoff, kbh + hoff);
                gl_lds16(Kl + sb + hoff, kbl + hoff);
                gl_lds16(Qh + sb + hoff, qbh + hoff);
                gl_lds16(Ql + sb + hoff, qbl + hoff);
                gl_lds16(Vt + vb + hoff, vbt + hoff);
            }
        }
        __syncthreads();

        // ---- QK: acc1 = Q·K^T, acc2 = K·Q^T (f16 split, 3 chains each) ----
        f32x4 a1[4], a2[4];
#pragma unroll
        for (int i = 0; i < 4; ++i) {
            a1[i] = (f32x4){0.f, 0.f, 0.f, 0.f};
            a2[i] = (f32x4){0.f, 0.f, 0.f, 0.f};
        }
#pragma unroll
        for (int kh = 0; kh < 2; ++kh) {
#pragma unroll
            for (int sub = 0; sub < 4; ++sub) {
                const int off = (sub * 16 + n) * 64 + (((q + kh * 4) ^ swz) << 3);
                h16x8 KBh = *(const h16x8*)&kbh[off];
                h16x8 KBl = *(const h16x8*)&kbl[off];
                h16x8 QBh = *(const h16x8*)&qbh[off];
                h16x8 QBl = *(const h16x8*)&qbl[off];
                f32x4 x1 = a1[sub], x2 = a2[sub];
                x1 = __builtin_amdgcn_mfma_f32_16x16x32_f16(QAh[kh], KBh, x1, 0, 0, 0);
                x1 = __builtin_amdgcn_mfma_f32_16x16x32_f16(QAh[kh], KBl, x1, 0, 0, 0);
                x1 = __builtin_amdgcn_mfma_f32_16x16x32_f16(QAl[kh], KBh, x1, 0, 0, 0);
                x2 = __builtin_amdgcn_mfma_f32_16x16x32_f16(KAh[kh], QBh, x2, 0, 0, 0);
                x2 = __builtin_amdgcn_mfma_f32_16x16x32_f16(KAh[kh], QBl, x2, 0, 0, 0);
                x2 = __builtin_amdgcn_mfma_f32_16x16x32_f16(KAl[kh], QBh, x2, 0, 0, 0);
                a1[sub] = x1; a2[sub] = x2;
            }
        }

        // ---- elementwise chain (C-layout: row q*4+r, col sub*16+n) ----
#pragma unroll
        for (int sub = 0; sub < 4; ++sub) {
            const int s = s0 + sub * 16 + n;
#pragma unroll
            for (int r = 0; r < 4; ++r) {
                const int l = lbase + r;
                const size_t pidx = ((size_t)h * Ln + l) * (size_t)Sn + s;
                float ph = phi[pidx];
                float uu = u[pidx];
                float hm = hard[(size_t)l * Sn + s];
                float cm = a1[sub][r] - a2[sub][r];
                // tanh(c1*cm) = 1 - 2/(exp(c2*cm)+1)
                float x = 1.0f - 2.0f * frcp(__expf(c2 * cm) + 1.0f);
                // tanh-form gelu: x * sigmoid(1.5957691*(x + 0.044715 x^3))
                float t = x * fmaf(0.044715f * x, x, 1.0f);
                float g = x * frcp(1.0f + __expf(-1.59576912161f * t));
                // gumbel-sigmoid mask
                float z = (__logf((uu + 1e-8f) * frcp(1.0f - uu + 1e-8f)) + ph) * itau;
                float m = frcp(1.0f + __expf(-z));
                float att = 0.125f * g * m * hm;
                Aout[(((size_t)b * Hn + h) * Ln + l) * (size_t)Sn + s] = att;
                entp[r] += att * __logf(fmaxf(att, 1e-8f));
                plds[w][(q * 4 + r) * 72 + sub * 16 + n] = (_Float16)att;
            }
        }

        // ---- PV: accV += P · V (P A-frags from LDS, V^T B-frags) ----
        {
            const _Float16* pw = &plds[w][0];
#pragma unroll
            for (int kh = 0; kh < 2; ++kh) {
                h16x8 Pf = *(const h16x8*)&pw[n * 72 + q * 8 + kh * 32];
#pragma unroll
                for (int sub = 0; sub < 4; ++sub) {
                    h16x8 Vf = *(const h16x8*)&vbt[(sub * 16 + n) * 64 + (((q + kh * 4) ^ swz) << 3)];
                    accV[sub] = __builtin_amdgcn_mfma_f32_16x16x32_f16(Pf, Vf, accV[sub], 0, 0, 0);
                }
            }
        }
    }

    // ---- epilogue: V partial sums via atomics (2 s-half blocks per l-tile) ----
#pragma unroll
    for (int sub = 0; sub < 4; ++sub) {
#pragma unroll
        for (int r = 0; r < 4; ++r) {
            const int l = l0 + w * 16 + q * 4 + r;
            atomicAdd(Vout + (((size_t)b * Ln + l) * Hn + h) * En + sub * 16 + n, accV[sub][r]);
        }
    }
    // ---- entropy: quad-row reduce over 16 lanes, atomic partial ----
#pragma unroll
    for (int r = 0; r < 4; ++r) {
        float v = entp[r];
        v += __shfl_xor(v, 1);
        v += __shfl_xor(v, 2);
        v += __shfl_xor(v, 4);
        v += __shfl_xor(v, 8);
        if (n == 0) {
            atomicAdd(entOut + ((size_t)b * Hn + h) * Ln + lbase + r, -v);
        }
    }
}

extern "C" void kernel_launch(void* const* d_in, const int* in_sizes, int n_in,
                              void* d_out, int out_size, void* d_ws, size_t ws_size,
                              hipStream_t stream) {
    (void)in_sizes; (void)n_in; (void)ws_size; (void)out_size;

    const float* Q    = (const float*)d_in[0];   // (B,L,H,E)
    const float* K    = (const float*)d_in[1];   // (B,S,H,E)
    const float* Vv   = (const float*)d_in[2];   // (B,S,H,E)
    const float* phi  = (const float*)d_in[3];   // (H,L,S)
    const float* lg   = (const float*)d_in[4];
    const float* ltau = (const float*)d_in[5];
    const float* ltc  = (const float*)d_in[6];
    const float* hard = (const float*)d_in[7];   // (L,S)
    const float* u    = (const float*)d_in[8];   // (H,L,S)

    float* out  = (float*)d_out;
    float* Vout = out;                                 // B*L*H*E
    float* Aout = out + (size_t)Bn * Ln * Hn * En;     // B*H*L*S
    float* ent  = Aout + (size_t)Bn * Hn * Ln * Sn;    // B*H*L

    const size_t NE = (size_t)32 * 1024 * 64;          // 2.1M halves per array
    _Float16* Qh = (_Float16*)d_ws;
    _Float16* Ql = Qh + NE;
    _Float16* Kh = Ql + NE;
    _Float16* Kl = Kh + NE;
    _Float16* Vt = Kl + NE;

    hipMemsetAsync(Vout, 0, (size_t)Bn * Ln * Hn * En * sizeof(float), stream);
    hipMemsetAsync(ent, 0, (size_t)Bn * Hn * Ln * sizeof(float), stream);
    prep<<<dim3(16, 32), 256, 0, stream>>>(Q, K, Vv, Qh, Ql, Kh, Kl, Vt);
    fused_lie<<<dim3(32, Hn, Bn), 256, 0, stream>>>(Qh, Ql, Kh, Kl, Vt, phi, u, hard,
                                                    lg, ltau, ltc, Aout, Vout, ent);
}